// Round 12
// baseline (480.412 us; speedup 1.0000x reference)
//
#include <hip/hip_runtime.h>
#include <stdint.h>
#include <math.h>

typedef unsigned short u16;
typedef __attribute__((ext_vector_type(8))) short bf16x8;
typedef __attribute__((ext_vector_type(8))) short short8;
typedef __attribute__((ext_vector_type(4))) float f32x4;
typedef __attribute__((ext_vector_type(4))) unsigned short u16x4;

#define NB 16
#define TDr 256
#define TPr 1024
#define DM 512
#define NH 8
#define DHEAD 64

__device__ __forceinline__ float us2f(u16 u) {
  union { float f; unsigned int i; } x; x.i = ((unsigned int)u) << 16; return x.f;
}
__device__ __forceinline__ u16 f2us(float f) {
  union { float fl; unsigned int i; } x; x.fl = f;
  unsigned int u = x.i;
  return (u16)((u + 0x7fffu + ((u >> 16) & 1u)) >> 16);  // RNE
}

// ---------------------------------------------------------------------------
__global__ __launch_bounds__(64) void detect_kernel(const u16* __restrict__ raw,
                                                    int* __restrict__ flag)
{
  const int lane = threadIdx.x;
  float mx = 0.f;
  for (int i = lane; i < 256; i += 64) {
    float v = us2f(raw[i]);
    v = fabsf(v);
    if (isfinite(v)) mx = fmaxf(mx, v); else mx = 1e30f;
  }
#pragma unroll
  for (int o = 32; o; o >>= 1) mx = fmaxf(mx, __shfl_xor(mx, o));
  if (lane == 0) flag[0] = (mx > 1e10f) ? 1 : 0;
}

// ---------------------------------------------------------------------------
struct CvtDesc { const void* src; unsigned long dst_off; int n; };
struct CvtTable { CvtDesc d[28]; };

__global__ __launch_bounds__(256) void cvt_kernel(CvtTable t, u16* __restrict__ base,
                                                  const int* __restrict__ flag)
{
  const CvtDesc d = t.d[blockIdx.y];
  u16* dst = base + d.dst_off;
  const int isf32 = flag[0];
  const int stride = gridDim.x * 256;
  const int tid0 = blockIdx.x * 256 + threadIdx.x;
  if (d.n >= 8) {
    const int n8 = d.n >> 3;
    if (isf32) {
      const float* s = (const float*)d.src;
      for (int i = tid0; i < n8; i += stride) {
        f32x4 a = *(const f32x4*)&s[i * 8];
        f32x4 b = *(const f32x4*)&s[i * 8 + 4];
        short8 o;
        o[0]=(short)f2us(a[0]); o[1]=(short)f2us(a[1]); o[2]=(short)f2us(a[2]); o[3]=(short)f2us(a[3]);
        o[4]=(short)f2us(b[0]); o[5]=(short)f2us(b[1]); o[6]=(short)f2us(b[2]); o[7]=(short)f2us(b[3]);
        *(short8*)&dst[i * 8] = o;
      }
    } else {
      const short8* s = (const short8*)d.src;
      for (int i = tid0; i < n8; i += stride) *(short8*)&dst[i * 8] = s[i];
    }
  } else {
    if (isf32) {
      const float* s = (const float*)d.src;
      for (int i = tid0; i < d.n; i += stride) dst[i] = f2us(s[i]);
    } else {
      const u16* s = (const u16*)d.src;
      for (int i = tid0; i < d.n; i += stride) dst[i] = s[i];
    }
  }
}

// ---------------------------------------------------------------------------
// Transpose raw input (f32 or bf16 per flag) -> bf16 W^T
// ---------------------------------------------------------------------------
struct TTab { const void* in; u16* out; int R, C; };
struct TTable { TTab d[14]; };

__global__ __launch_bounds__(256) void transpose_all(TTable tt, const int* __restrict__ flag)
{
  const TTab d = tt.d[blockIdx.z];
  const int isf32 = flag[0];
  __shared__ u16 t[32][33];
  const int tx = threadIdx.x & 31, ty = threadIdx.x >> 5;
  for (int r0 = blockIdx.y * 32; r0 < d.R; r0 += gridDim.y * 32) {
    for (int c0 = blockIdx.x * 32; c0 < d.C; c0 += gridDim.x * 32) {
#pragma unroll
      for (int i = 0; i < 4; ++i) {
        const long idx = (long)(r0 + ty + 8*i) * d.C + c0 + tx;
        t[ty + 8*i][tx] = isf32 ? f2us(((const float*)d.in)[idx])
                                : ((const u16*)d.in)[idx];
      }
      __syncthreads();
#pragma unroll
      for (int i = 0; i < 4; ++i)
        d.out[(long)(c0 + ty + 8*i) * d.R + r0 + tx] = t[tx][ty + 8*i];
      __syncthreads();
    }
  }
}

// ---------------------------------------------------------------------------
// Shared GEMM core: 128x128 tile, BK=32, 3-deep global_load_lds pipeline
// (stage 2 tiles ahead) with counted vmcnt. lda = ldb = K.
// WAR audit: stage(t+3)->buf t%3 issued after barrier ending compute(t);
// vmcnt(8) before compute(t) leaves tiles t+1,t+2 (8 loads) in flight.
// ---------------------------------------------------------------------------
template<int BM, int BN>
__device__ __forceinline__ void gemm_core(
    const u16* __restrict__ Ab, const u16* __restrict__ Bb,
    int K, int tid, f32x4 (&acc)[BM/32][BN/32])
{
  constexpr int BK = 32;
  constexpr int FM = BM / 32;
  constexpr int FN = BN / 32;
  __shared__ __align__(16) u16 As[3][BM * BK];
  __shared__ __align__(16) u16 Bs[3][BN * BK];

  const int lane = tid & 63;
  const int wm = (tid >> 6) >> 1;
  const int wn = (tid >> 6) & 1;

#pragma unroll
  for (int i = 0; i < FM; ++i)
#pragma unroll
    for (int j = 0; j < FN; ++j)
      acc[i][j] = (f32x4){0.f, 0.f, 0.f, 0.f};

  auto stage = [&](int buf, int k0) {
#pragma unroll
    for (int c = tid; c < BM * BK / 8; c += 256) {
      const int r  = c >> 2;
      const int kk = (c & 3) << 3;
      __builtin_amdgcn_global_load_lds(
          (const __attribute__((address_space(1))) uint32_t*)(Ab + (long)r * K + k0 + kk),
          (__attribute__((address_space(3))) uint32_t*)(&As[buf][c * 8]), 16, 0, 0);
    }
#pragma unroll
    for (int c = tid; c < BN * BK / 8; c += 256) {
      const int r  = c >> 2;
      const int kk = (c & 3) << 3;
      __builtin_amdgcn_global_load_lds(
          (const __attribute__((address_space(1))) uint32_t*)(Bb + (long)r * K + k0 + kk),
          (__attribute__((address_space(3))) uint32_t*)(&Bs[buf][c * 8]), 16, 0, 0);
    }
  };

  const int nt = K / BK;
  stage(0, 0);
  if (nt > 1) stage(1, BK);
  if (nt > 2) stage(2, 2 * BK);

  for (int t = 0; t < nt; ++t) {
    if (t + 2 < nt)      asm volatile("s_waitcnt vmcnt(8)" ::: "memory");
    else if (t + 1 < nt) asm volatile("s_waitcnt vmcnt(4)" ::: "memory");
    else                 asm volatile("s_waitcnt vmcnt(0)" ::: "memory");
    asm volatile("s_barrier" ::: "memory");
    __builtin_amdgcn_sched_barrier(0);

    const int cur = t % 3;
    bf16x8 af[FM], bfv[FN];
#pragma unroll
    for (int i = 0; i < FM; ++i)
      af[i] = *(const bf16x8*)&As[cur][(wm * (BM/2) + i*16 + (lane & 15)) * BK + ((lane >> 4) << 3)];
#pragma unroll
    for (int j = 0; j < FN; ++j)
      bfv[j] = *(const bf16x8*)&Bs[cur][(wn * (BN/2) + j*16 + (lane & 15)) * BK + ((lane >> 4) << 3)];
#pragma unroll
    for (int i = 0; i < FM; ++i)
#pragma unroll
      for (int j = 0; j < FN; ++j)
        acc[i][j] = __builtin_amdgcn_mfma_f32_16x16x32_bf16(af[i], bfv[j], acc[i][j], 0, 0, 0);

    __builtin_amdgcn_sched_barrier(0);
    asm volatile("s_barrier" ::: "memory");
    __builtin_amdgcn_sched_barrier(0);
    if (t + 3 < nt) stage(cur, (t + 3) * BK);
  }
}

// ---------------------------------------------------------------------------
// Fused projection pair (epilogue routes 512-col ranges; V head-transposed)
// ---------------------------------------------------------------------------
struct ProjSet {
  const u16 *A, *W, *bE, *bQ, *bK, *bV;
  u16 *H, *Q, *Kc, *VT;
  int ntokLog, mtiles;
};

__global__ __launch_bounds__(256, 3) void proj_pair(ProjSet s0, ProjSet s1)
{
  const ProjSet S = blockIdx.z ? s1 : s0;
  if ((int)blockIdx.x >= S.mtiles) return;
  const int tid = threadIdx.x;
  const int lane = tid & 63;
  const int wm = (tid >> 6) >> 1, wn = (tid >> 6) & 1;
  const int r16 = lane & 15, rr4 = (lane >> 4) << 2;
  const long row0 = (long)blockIdx.x * 128;
  const long col0 = (long)blockIdx.y * 128;

  f32x4 acc[4][4];
  gemm_core<128,128>(S.A + row0 * 512, S.W + col0 * 512, 512, tid, acc);

  const int range = (int)(col0 >> 9);
  const u16* bp = range == 0 ? S.bE : range == 1 ? S.bQ : range == 2 ? S.bK : S.bV;
  u16* dst = range == 0 ? S.H : range == 1 ? S.Q : S.Kc;
  const int ntok = 1 << S.ntokLog;

#pragma unroll
  for (int i = 0; i < 4; ++i) {
    const long gr0 = row0 + wm*64 + i*16 + rr4;
#pragma unroll
    for (int j = 0; j < 4; ++j) {
      const int cr = (int)(col0 & 511) + wn*64 + j*16 + r16;
      const float badd = us2f(bp[cr]);
      if (range == 3) {
        const long b = gr0 >> S.ntokLog;
        const long t0 = gr0 & (ntok - 1);
        u16x4 pk;
#pragma unroll
        for (int r = 0; r < 4; ++r) pk[r] = f2us(acc[i][j][r] + badd);
        *(u16x4*)&S.VT[((long)b * 512 + cr) * ntok + t0] = pk;
      } else if (range == 0) {
#pragma unroll
        for (int r = 0; r < 4; ++r) {
          float v = acc[i][j][r] + badd;
          v = v / (1.f + __expf(-v));
          dst[(gr0 + r) * 512 + cr] = f2us(v);
        }
      } else {
#pragma unroll
        for (int r = 0; r < 4; ++r)
          dst[(gr0 + r) * 512 + cr] = f2us(acc[i][j][r] + badd);
      }
    }
  }
}

// ---------------------------------------------------------------------------
struct Gm { const u16* A; const u16* Bt; const u16* bias; u16* C; int mtiles; };

template<int SILU>
__global__ __launch_bounds__(256, 3) void gemm_pair(Gm g0, Gm g1, int ldc, int K)
{
  const Gm G = blockIdx.z ? g1 : g0;
  if ((int)blockIdx.x >= G.mtiles) return;
  const int tid = threadIdx.x;
  const int lane = tid & 63;
  const int wm = (tid >> 6) >> 1, wn = (tid >> 6) & 1;
  const int r16 = lane & 15, rr4 = (lane >> 4) << 2;
  const long row0 = (long)blockIdx.x * 128;
  const long col0 = (long)blockIdx.y * 128;

  f32x4 acc[4][4];
  gemm_core<128,128>(G.A + row0 * (long)K, G.Bt + col0 * (long)K, K, tid, acc);

#pragma unroll
  for (int i = 0; i < 4; ++i) {
    const long gr0 = row0 + wm*64 + i*16 + rr4;
#pragma unroll
    for (int j = 0; j < 4; ++j) {
      const long gc = col0 + wn*64 + j*16 + r16;
      const float badd = us2f(G.bias[gc]);
#pragma unroll
      for (int r = 0; r < 4; ++r) {
        float v = acc[i][j][r] + badd;
        if (SILU) v = v / (1.f + __expf(-v));
        G.C[(gr0 + r) * (long)ldc + gc] = f2us(v);
      }
    }
  }
}

// ---------------------------------------------------------------------------
// Fused attention body (round-8 proven structure), shared LDS by pointer.
// ---------------------------------------------------------------------------
template<int NKV, int RPW>
__device__ __forceinline__ void attn_body(
    const u16* __restrict__ Qp, const u16* __restrict__ Kp,
    const u16* __restrict__ Vt, const float* __restrict__ lb,
    u16* __restrict__ Aout, int M, u16* __restrict__ Ps)
{
  constexpr int NC = NKV >> 7;
  constexpr int FI = RPW / 16;
  constexpr int NS = 4 * FI;
  constexpr int QT = 4 * RPW;
  constexpr int PLD = 136;

  const int tid  = threadIdx.x;
  const int lane = tid & 63;
  const int w    = tid >> 6;
  const int bh = blockIdx.y;
  const int b = bh >> 3, h = bh & 7;
  const long q0 = (long)blockIdx.x * QT;

  const u16* Qb = Qp + ((long)b * M + q0) * DM + h * DHEAD;
  const u16* Kb = Kp + (long)b * NKV * DM + h * DHEAD;
  const u16* Vb = Vt + ((long)b * DM + h * DHEAD) * NKV;
  const float* lbb = lb + (long)b * NKV;

  const int r16 = lane & 15;
  const int k8  = (lane >> 4) << 3;
  const int rr4 = (lane >> 4) << 2;
  const float SCALE = 0.125f;
  u16* Pw = Ps + (w * RPW) * PLD;

  bf16x8 qa[FI][2];
#pragma unroll
  for (int i = 0; i < FI; ++i)
#pragma unroll
    for (int kc = 0; kc < 2; ++kc)
      qa[i][kc] = *(const bf16x8*)&Qb[(long)(w*RPW + i*16 + r16) * DM + kc*32 + k8];

  f32x4 acc_o[FI][4];
#pragma unroll
  for (int i = 0; i < FI; ++i)
#pragma unroll
    for (int jo = 0; jo < 4; ++jo)
      acc_o[i][jo] = (f32x4){0.f, 0.f, 0.f, 0.f};
  float mrow[NS], lrow[NS];
#pragma unroll
  for (int s = 0; s < NS; ++s) { mrow[s] = -1e30f; lrow[s] = 0.f; }

#pragma unroll
  for (int c = 0; c < NC; ++c) {
    const int t0 = c * 128;
    f32x4 acc_s[FI][8];
#pragma unroll
    for (int i = 0; i < FI; ++i)
#pragma unroll
      for (int j = 0; j < 8; ++j)
        acc_s[i][j] = (f32x4){0.f, 0.f, 0.f, 0.f};
#pragma unroll
    for (int j = 0; j < 8; ++j) {
      const long trow = t0 + j*16 + r16;
      bf16x8 kb0 = *(const bf16x8*)&Kb[trow * DM + k8];
      bf16x8 kb1 = *(const bf16x8*)&Kb[trow * DM + 32 + k8];
#pragma unroll
      for (int i = 0; i < FI; ++i) {
        acc_s[i][j] = __builtin_amdgcn_mfma_f32_16x16x32_bf16(qa[i][0], kb0, acc_s[i][j], 0, 0, 0);
        acc_s[i][j] = __builtin_amdgcn_mfma_f32_16x16x32_bf16(qa[i][1], kb1, acc_s[i][j], 0, 0, 0);
      }
    }

    float lbv[8];
#pragma unroll
    for (int j = 0; j < 8; ++j) lbv[j] = lbb[t0 + j*16 + r16];
    float pm[NS];
#pragma unroll
    for (int s = 0; s < NS; ++s) pm[s] = -1e30f;
#pragma unroll
    for (int i = 0; i < FI; ++i)
#pragma unroll
      for (int j = 0; j < 8; ++j)
#pragma unroll
        for (int r = 0; r < 4; ++r) {
          float v = acc_s[i][j][r] * SCALE + lbv[j];
          acc_s[i][j][r] = v;
          pm[i*4 + r] = fmaxf(pm[i*4 + r], v);
        }
#pragma unroll
    for (int s = 0; s < NS; ++s) {
#pragma unroll
      for (int o = 1; o < 16; o <<= 1) pm[s] = fmaxf(pm[s], __shfl_xor(pm[s], o));
    }
    float sc[NS];
#pragma unroll
    for (int s = 0; s < NS; ++s) {
      const float mn = fmaxf(mrow[s], pm[s]);
      sc[s] = __expf(mrow[s] - mn);
      mrow[s] = mn;
      lrow[s] *= sc[s];
    }
#pragma unroll
    for (int i = 0; i < FI; ++i)
#pragma unroll
      for (int jo = 0; jo < 4; ++jo)
#pragma unroll
        for (int r = 0; r < 4; ++r)
          acc_o[i][jo][r] *= sc[i*4 + r];

    float ls[NS];
#pragma unroll
    for (int s = 0; s < NS; ++s) ls[s] = 0.f;
#pragma unroll
    for (int i = 0; i < FI; ++i)
#pragma unroll
      for (int j = 0; j < 8; ++j)
#pragma unroll
        for (int r = 0; r < 4; ++r) {
          const float p = __expf(acc_s[i][j][r] - mrow[i*4 + r]);
          ls[i*4 + r] += p;
          Pw[(i*16 + rr4 + r) * PLD + j*16 + r16] = f2us(p);
        }
#pragma unroll
    for (int s = 0; s < NS; ++s) {
#pragma unroll
      for (int o = 1; o < 16; o <<= 1) ls[s] += __shfl_xor(ls[s], o);
      lrow[s] += ls[s];
    }

    asm volatile("s_waitcnt lgkmcnt(0)" ::: "memory");
    __builtin_amdgcn_sched_barrier(0);

#pragma unroll
    for (int kc = 0; kc < 4; ++kc) {
      bf16x8 pa[FI];
#pragma unroll
      for (int i = 0; i < FI; ++i)
        pa[i] = *(const bf16x8*)&Pw[(i*16 + r16) * PLD + kc*32 + k8];
#pragma unroll
      for (int jo = 0; jo < 4; ++jo) {
        bf16x8 vb = *(const bf16x8*)&Vb[(long)(jo*16 + r16) * NKV + t0 + kc*32 + k8];
#pragma unroll
        for (int i = 0; i < FI; ++i)
          acc_o[i][jo] = __builtin_amdgcn_mfma_f32_16x16x32_bf16(pa[i], vb, acc_o[i][jo], 0, 0, 0);
      }
    }
    __builtin_amdgcn_sched_barrier(0);
  }

  float linv[NS];
#pragma unroll
  for (int s = 0; s < NS; ++s) linv[s] = 1.f / lrow[s];
  u16* Ob = Aout + ((long)b * M + q0) * DM + h * DHEAD;
#pragma unroll
  for (int i = 0; i < FI; ++i)
#pragma unroll
    for (int jo = 0; jo < 4; ++jo)
#pragma unroll
      for (int r = 0; r < 4; ++r) {
        const long row = w*RPW + i*16 + rr4 + r;
        Ob[row * DM + jo*16 + r16] = f2us(acc_o[i][jo][r] * linv[i*4 + r]);
      }
}

// merged attention: z=0 -> p2d (NKV=256, RPW=32); z=1 -> d2p (NKV=1024, RPW=16)
__global__ __launch_bounds__(256) void attn_both(
    const u16* Qp0, const u16* Kp0, const u16* Vt0, const float* lb0, u16* Ao0,
    const u16* Qp1, const u16* Kp1, const u16* Vt1, const float* lb1, u16* Ao1)
{
  __shared__ __align__(16) u16 Ps[4 * 32 * 136];
  if (blockIdx.z == 0) {
    attn_body<TDr, 32>(Qp0, Kp0, Vt0, lb0, Ao0, TPr, Ps);
  } else {
    if ((int)blockIdx.x >= TDr / 64) return;
    attn_body<TPr, 16>(Qp1, Kp1, Vt1, lb1, Ao1, TDr, Ps);
  }
}

// ---------------------------------------------------------------------------
struct LnR { const u16* X; const u16* P; const u16* g; const u16* b; u16* out; int rows; };

__global__ __launch_bounds__(256) void ln_res_pair(LnR a0, LnR a1)
{
  const LnR A = blockIdx.z ? a1 : a0;
  const int row = blockIdx.x * 4 + (threadIdx.x >> 6);
  if (row >= A.rows) return;
  const int lane = threadIdx.x & 63;
  const u16* pr = A.P + (long)row * DM;
  const u16* xr = A.X + (long)row * DM;
  float v[8], s = 0.f, s2 = 0.f;
#pragma unroll
  for (int i = 0; i < 8; ++i) {
    const int jx = i * 64 + lane;
    float t = us2f(pr[jx]) + us2f(xr[jx]);
    v[i] = t; s += t; s2 += t * t;
  }
#pragma unroll
  for (int o = 32; o; o >>= 1) { s += __shfl_xor(s, o); s2 += __shfl_xor(s2, o); }
  const float mean = s * (1.f / DM);
  const float var  = s2 * (1.f / DM) - mean * mean;
  const float rstd = rsqrtf(fmaxf(var, 0.f) + 1e-5f);
#pragma unroll
  for (int i = 0; i < 8; ++i) {
    const int jx = i * 64 + lane;
    A.out[(long)row * DM + jx] = f2us((v[i] - mean) * rstd * us2f(A.g[jx]) + us2f(A.b[jx]));
  }
}

// ---------------------------------------------------------------------------
struct LnF { const u16* P; const u16* g; const u16* b; long oofs; int rows; };

__global__ __launch_bounds__(256) void ln_final_pair(LnF a0, LnF a1,
                                                     void* __restrict__ outb,
                                                     const int* __restrict__ flag)
{
  const LnF A = blockIdx.z ? a1 : a0;
  const int row = blockIdx.x * 4 + (threadIdx.x >> 6);
  if (row >= A.rows) return;
  const int lane = threadIdx.x & 63;
  const u16* pr = A.P + (long)row * DM;
  float v[8], s = 0.f, s2 = 0.f;
#pragma unroll
  for (int i = 0; i < 8; ++i) {
    const int jx = i * 64 + lane;
    float t = us2f(pr[jx]);
    v[i] = t; s += t; s2 += t * t;
  }
#pragma unroll
  for (int o = 32; o; o >>= 1) { s += __shfl_xor(s, o); s2 += __shfl_xor(s2, o); }
  const float mean = s * (1.f / DM);
  const float var  = s2 * (1.f / DM) - mean * mean;
  const float rstd = rsqrtf(fmaxf(var, 0.f) + 1e-5f);
  const int isf32 = flag[0];
#pragma unroll
  for (int i = 0; i < 8; ++i) {
    const int jx = i * 64 + lane;
    const float ov = (v[i] - mean) * rstd * us2f(A.g[jx]) + us2f(A.b[jx]);
    if (isf32) ((float*)outb)[A.oofs + (long)row * DM + jx] = ov;
    else       ((u16*)outb)[A.oofs + (long)row * DM + jx] = f2us(ov);
  }
}

// ---------------------------------------------------------------------------
struct Gt { const u16* H; const u16* W2; const u16* b2; long oofs; float* lb; int rows; };

__global__ __launch_bounds__(256) void gate_pair(Gt a0, Gt a1,
                                                 const int* __restrict__ kptr,
                                                 void* __restrict__ outb,
                                                 const int* __restrict__ flag)
{
  const Gt A = blockIdx.z ? a1 : a0;
  const int row = blockIdx.x * 4 + (threadIdx.x >> 6);
  if (row >= A.rows) return;
  const int lane = threadIdx.x & 63;
  const u16* hr = A.H + (long)row * DM;
  float p1 = 0.f, p2 = 0.f, p3 = 0.f;
#pragma unroll
  for (int i = 0; i < 8; ++i) {
    const int idx = i * 64 + lane;
    const float hv = us2f(hr[idx]);
    const u16x4 w = *(const u16x4*)&A.W2[idx * 4];
    p1 += hv * us2f(w[1]);
    p2 += hv * us2f(w[2]); p3 += hv * us2f(w[3]);
  }
#pragma unroll
  for (int o = 32; o; o >>= 1) {
    p1 += __shfl_xor(p1, o);
    p2 += __shfl_xor(p2, o); p3 += __shfl_xor(p3, o);
  }
  if (lane == 0) {
    const float nu = p1 + us2f(A.b2[1]);
    const float al = p2 + us2f(A.b2[2]);
    const float be = p3 + us2f(A.b2[3]);
    auto sp = [](float x) { return x > 20.f ? x : log1pf(expf(x)); };
    const float spn = sp(nu) + 1e-6f;
    const float spa = sp(al);
    const float spb = sp(be) + 1e-6f;
    const float sig = spb / (spn * spa);
    const float kk = (float)kptr[0];
    float gg = expf(-kk * sig);
    gg = fminf(fmaxf(gg, 0.05f), 1.f);
    if (flag[0]) ((float*)outb)[A.oofs + row] = gg;
    else         ((u16*)outb)[A.oofs + row] = f2us(gg);
    A.lb[row] = logf(gg + 1e-12f);
  }
}

// ---------------------------------------------------------------------------
extern "C" void kernel_launch(void* const* d_in, const int* in_sizes, int n_in,
                              void* d_out, int out_size, void* d_ws, size_t ws_size,
                              hipStream_t stream)
{
  const int* kptr = (const int*)d_in[2];

  uint8_t* base = (uint8_t*)d_ws;
  size_t off = 0;
  auto take = [&](size_t bytes) -> void* {
    void* p = base + off;
    off += (bytes + 255) & ~(size_t)255;
    return p;
  };
  int* FLAG = (int*)take(256);

  const int sizes[42] = {
    2097152, 8388608,
    262144, 512, 2048, 4,
    262144, 512, 2048, 4,
    262144,262144,262144,262144, 512,512,512,512, 512,512,
    262144,262144,262144,262144, 512,512,512,512, 512,512,
    1048576, 2048, 1048576, 512, 512, 512,
    1048576, 2048, 1048576, 512, 512, 512
  };
  // canon indices whose tensors are consumed ONLY via transposed copies:
  // 2(evid_w1) 6(evip_w1) 10,11,12,13(p2d w*) 20,21,22,23(d2p w*)
  // 30,32(ffnd w1,w2) 36,38(ffnp w1,w2)
  u16* canon[42];
  u16* cbase = (u16*)take(17319944ul * 2 + 256);
  {
    unsigned long coff = 0;
    for (int i = 0; i < 42; ++i) {
      canon[i] = cbase + coff;
      coff += (unsigned long)((sizes[i] + 7) & ~7);
    }
  }
  const u16 *HdC = canon[0], *HpC = canon[1];
  const u16 *evid_b1 = canon[3], *evid_w2 = canon[4], *evid_b2 = canon[5];
  const u16 *evip_b1 = canon[7], *evip_w2 = canon[8], *evip_b2 = canon[9];
  const u16 *p2d_bq = canon[14], *p2d_bk = canon[15], *p2d_bv = canon[16], *p2d_bo = canon[17];
  const u16 *p2d_lng = canon[18], *p2d_lnb = canon[19];
  const u16 *d2p_bq = canon[24], *d2p_bk = canon[25], *d2p_bv = canon[26], *d2p_bo = canon[27];
  const u16 *d2p_lng = canon[28], *d2p_lnb = canon[29];
  const u16 *ffnd_b1 = canon[31], *ffnd_b2 = canon[33];
  const u16 *ffnd_lng = canon[34], *ffnd_lnb = canon[35];
  const u16 *ffnp_b1 = canon[37], *ffnp_b2 = canon[39];
  const u16 *ffnp_lng = canon[40], *ffnp_lnb = canon[41];

  u16* HpW = (u16*)take((size_t)2048*512*2);
  u16* HdW = (u16*)take((size_t)2048*512*2);
  u16* woT_p = (u16*)take((size_t)512*512*2);
  u16* woT_d = (u16*)take((size_t)512*512*2);
  u16* ffnp_w1T = (u16*)take((size_t)2048*512*2);
  u16* ffnp_w2T = (u16*)take((size_t)512*2048*2);
  u16* ffnd_w1T = (u16*)take((size_t)2048*512*2);
  u16* ffnd_w2T = (u16*)take((size_t)512*2048*2);

  u16* HBUF_p = (u16*)take((size_t)16384*512*2);
  u16* HBUF_d = (u16*)take((size_t)4096*512*2);
  u16* QBUF_p = (u16*)take((size_t)16384*512*2);
  u16* QBUF_d = (u16*)take((size_t)4096*512*2);
  u16* KBUF_p = (u16*)take((size_t)16384*512*2);
  u16* KBUF_d = (u16*)take((size_t)4096*512*2);
  u16* VT_p   = (u16*)take((size_t)16384*512*2);
  u16* VT_d   = (u16*)take((size_t)4096*512*2);
  u16* ABUF_p = (u16*)take((size_t)16384*512*2);
  u16* ABUF_d = (u16*)take((size_t)4096*512*2);
  u16* HP2  = (u16*)take((size_t)16384*512*2);
  u16* HD2  = (u16*)take((size_t)4096*512*2);
  float* LBD  = (float*)take((size_t)NB*TDr*4);
  float* LBP  = (float*)take((size_t)NB*TPr*4);
  if (off > ws_size) return;

  u16* PBUF_p = HBUF_p;
  u16* PBUF_d = HBUF_d;
  u16* SBUF_p = QBUF_p;
  u16* SBUF_d = SBUF_p + (size_t)16384*2048;

  const long O_HD = 0;
  const long O_HP = 2097152;
  const long O_GD = 10485760;
  const long O_GP = 10489856;

  detect_kernel<<<dim3(1), 64, 0, stream>>>((const u16*)d_in[0], FLAG);

  // canonicalize the 28 tensors that are read directly (skip the 14 weights)
  CvtTable tbl;
  {
    const int skip[14] = {2,6,10,11,12,13,20,21,22,23,30,32,36,38};
    int ii = 0;
    for (int ci = 0; ci < 42; ++ci) {
      bool sk = false;
      for (int s = 0; s < 14; ++s) if (skip[s] == ci) { sk = true; break; }
      if (sk) continue;
      tbl.d[ii].src = d_in[ci < 2 ? ci : ci + 1];
      tbl.d[ii].dst_off = (unsigned long)(canon[ci] - cbase);
      tbl.d[ii].n = sizes[ci];
      ++ii;
    }
  }
  cvt_kernel<<<dim3(64, 28), 256, 0, stream>>>(tbl, cbase, FLAG);

  // transpose the 14 weights straight from raw input (dtype via flag)
  TTable tt;
  {
    const TTab tts[14] = {
      {d_in[7],  HpW + 0*512*512, 512, 512},   // evip_w1
      {d_in[11], HpW + 1*512*512, 512, 512},   // p2d_wq
      {d_in[22], HpW + 2*512*512, 512, 512},   // d2p_wk
      {d_in[23], HpW + 3*512*512, 512, 512},   // d2p_wv
      {d_in[3],  HdW + 0*512*512, 512, 512},   // evid_w1
      {d_in[21], HdW + 1*512*512, 512, 512},   // d2p_wq
      {d_in[12], HdW + 2*512*512, 512, 512},   // p2d_wk
      {d_in[13], HdW + 3*512*512, 512, 512},   // p2d_wv
      {d_in[14], woT_p, 512, 512},             // p2d_wo
      {d_in[24], woT_d, 512, 512},             // d2p_wo
      {d_in[37], ffnp_w1T, 512, 2048},         // ffnp_w1
      {d_in[39], ffnp_w2T, 2048, 512},         // ffnp_w2
      {d_in[31], ffnd_w1T, 512, 2048},         // ffnd_w1
      {d_in[33], ffnd_w2T, 2048, 512},         // ffnd_w2
    };
    for (int i = 0; i < 14; ++i) tt.d[i] = tts[i];
  }
  transpose_all<<<dim3(16, 16, 14), 256, 0, stream>>>(tt, FLAG);

  // ---- fused projections ----
  ProjSet sp{HpC, HpW, evip_b1, p2d_bq, d2p_bk, d2p_bv,
             HBUF_p, QBUF_p, KBUF_p, VT_p, 10, 128};
  ProjSet sd{HdC, HdW, evid_b1, d2p_bq, p2d_bk, p2d_bv,
             HBUF_d, QBUF_d, KBUF_d, VT_d, 8, 32};
  proj_pair<<<dim3(128, 16, 2), 256, 0, stream>>>(sp, sd);

  // ---- gates (produce log-bias for attention) ----
  Gt gp{HBUF_p, evip_w2, evip_b2, O_GP, LBP, 16384};
  Gt gd{HBUF_d, evid_w2, evid_b2, O_GD, LBD, 4096};
  gate_pair<<<dim3(4096, 1, 2), 256, 0, stream>>>(gp, gd, kptr, d_out, FLAG);

  // ---- attention: both directions in one launch (compile-time NC each) ----
  attn_both<<<dim3(TPr/128, NB*NH, 2), 256, 0, stream>>>(
      QBUF_p, KBUF_d, VT_d, LBD, ABUF_p,
      QBUF_d, KBUF_p, VT_p, LBP, ABUF_d);

  // ---- output projections ----
  Gm wp{ABUF_p, woT_p, p2d_bo, PBUF_p, 128};
  Gm wd{ABUF_d, woT_d, d2p_bo, PBUF_d, 32};
  gemm_pair<0><<<dim3(128, 4, 2), 256, 0, stream>>>(wp, wd, 512, 512);

  // ---- residual LN ----
  LnR lp{HpC, PBUF_p, p2d_lng, p2d_lnb, HP2, 16384};
  LnR ld{HdC, PBUF_d, d2p_lng, d2p_lnb, HD2, 4096};
  ln_res_pair<<<dim3(4096, 1, 2), 256, 0, stream>>>(lp, ld);

  // ---- FFN1 (SiLU) ----
  Gm f1p{HP2, ffnp_w1T, ffnp_b1, SBUF_p, 128};
  Gm f1d{HD2, ffnd_w1T, ffnd_b1, SBUF_d, 32};
  gemm_pair<1><<<dim3(128, 16, 2), 256, 0, stream>>>(f1p, f1d, 2048, 512);

  // ---- FFN2 ----
  Gm f2p{SBUF_p, ffnp_w2T, ffnp_b2, PBUF_p, 128};
  Gm f2d{SBUF_d, ffnd_w2T, ffnd_b2, PBUF_d, 32};
  gemm_pair<0><<<dim3(128, 4, 2), 256, 0, stream>>>(f2p, f2d, 512, 2048);

  // ---- final LN -> d_out ----
  LnF fp{PBUF_p, ffnp_lng, ffnp_lnb, O_HP, 16384};
  LnF fd{PBUF_d, ffnd_lng, ffnd_lnb, O_HD, 4096};
  ln_final_pair<<<dim3(4096, 1, 2), 256, 0, stream>>>(fp, fd, d_out, FLAG);
}

// Round 13
// 431.212 us; speedup vs baseline: 1.1141x; 1.1141x over previous
//
#include <hip/hip_runtime.h>
#include <stdint.h>
#include <math.h>

typedef unsigned short u16;
typedef __attribute__((ext_vector_type(8))) short bf16x8;
typedef __attribute__((ext_vector_type(8))) short short8;
typedef __attribute__((ext_vector_type(4))) float f32x4;
typedef __attribute__((ext_vector_type(4))) unsigned short u16x4;

#define NB 16
#define TDr 256
#define TPr 1024
#define DM 512
#define NH 8
#define DHEAD 64

__device__ __forceinline__ float us2f(u16 u) {
  union { float f; unsigned int i; } x; x.i = ((unsigned int)u) << 16; return x.f;
}
__device__ __forceinline__ u16 f2us(float f) {
  union { float fl; unsigned int i; } x; x.fl = f;
  unsigned int u = x.i;
  return (u16)((u + 0x7fffu + ((u >> 16) & 1u)) >> 16);  // RNE
}

// ---------------------------------------------------------------------------
__global__ __launch_bounds__(64) void detect_kernel(const u16* __restrict__ raw,
                                                    int* __restrict__ flag)
{
  const int lane = threadIdx.x;
  float mx = 0.f;
  for (int i = lane; i < 256; i += 64) {
    float v = us2f(raw[i]);
    v = fabsf(v);
    if (isfinite(v)) mx = fmaxf(mx, v); else mx = 1e30f;
  }
#pragma unroll
  for (int o = 32; o; o >>= 1) mx = fmaxf(mx, __shfl_xor(mx, o));
  if (lane == 0) flag[0] = (mx > 1e10f) ? 1 : 0;
}

// ---------------------------------------------------------------------------
struct CvtDesc { const void* src; unsigned long dst_off; int n; };
struct CvtTable { CvtDesc d[28]; };

__global__ __launch_bounds__(256) void cvt_kernel(CvtTable t, u16* __restrict__ base,
                                                  const int* __restrict__ flag)
{
  const CvtDesc d = t.d[blockIdx.y];
  u16* dst = base + d.dst_off;
  const int isf32 = flag[0];
  const int stride = gridDim.x * 256;
  const int tid0 = blockIdx.x * 256 + threadIdx.x;
  if (d.n >= 8) {
    const int n8 = d.n >> 3;
    if (isf32) {
      const float* s = (const float*)d.src;
      for (int i = tid0; i < n8; i += stride) {
        f32x4 a = *(const f32x4*)&s[i * 8];
        f32x4 b = *(const f32x4*)&s[i * 8 + 4];
        short8 o;
        o[0]=(short)f2us(a[0]); o[1]=(short)f2us(a[1]); o[2]=(short)f2us(a[2]); o[3]=(short)f2us(a[3]);
        o[4]=(short)f2us(b[0]); o[5]=(short)f2us(b[1]); o[6]=(short)f2us(b[2]); o[7]=(short)f2us(b[3]);
        *(short8*)&dst[i * 8] = o;
      }
    } else {
      const short8* s = (const short8*)d.src;
      for (int i = tid0; i < n8; i += stride) *(short8*)&dst[i * 8] = s[i];
    }
  } else {
    if (isf32) {
      const float* s = (const float*)d.src;
      for (int i = tid0; i < d.n; i += stride) dst[i] = f2us(s[i]);
    } else {
      const u16* s = (const u16*)d.src;
      for (int i = tid0; i < d.n; i += stride) dst[i] = s[i];
    }
  }
}

// ---------------------------------------------------------------------------
// Transpose raw input (f32 or bf16 per flag) -> bf16 W^T
// ---------------------------------------------------------------------------
struct TTab { const void* in; u16* out; int R, C; };
struct TTable { TTab d[14]; };

__global__ __launch_bounds__(256) void transpose_all(TTable tt, const int* __restrict__ flag)
{
  const TTab d = tt.d[blockIdx.z];
  const int isf32 = flag[0];
  __shared__ u16 t[32][33];
  const int tx = threadIdx.x & 31, ty = threadIdx.x >> 5;
  for (int r0 = blockIdx.y * 32; r0 < d.R; r0 += gridDim.y * 32) {
    for (int c0 = blockIdx.x * 32; c0 < d.C; c0 += gridDim.x * 32) {
#pragma unroll
      for (int i = 0; i < 4; ++i) {
        const long idx = (long)(r0 + ty + 8*i) * d.C + c0 + tx;
        t[ty + 8*i][tx] = isf32 ? f2us(((const float*)d.in)[idx])
                                : ((const u16*)d.in)[idx];
      }
      __syncthreads();
#pragma unroll
      for (int i = 0; i < 4; ++i)
        d.out[(long)(c0 + ty + 8*i) * d.R + r0 + tx] = t[tx][ty + 8*i];
      __syncthreads();
    }
  }
}

// ---------------------------------------------------------------------------
// Shared GEMM core: 128x128 tile, BK=32, 3-deep global_load_lds pipeline
// (stage 2 tiles ahead) with counted vmcnt. lda = ldb = K.
// ---------------------------------------------------------------------------
template<int BM, int BN>
__device__ __forceinline__ void gemm_core(
    const u16* __restrict__ Ab, const u16* __restrict__ Bb,
    int K, int tid, f32x4 (&acc)[BM/32][BN/32])
{
  constexpr int BK = 32;
  constexpr int FM = BM / 32;
  constexpr int FN = BN / 32;
  __shared__ __align__(16) u16 As[3][BM * BK];
  __shared__ __align__(16) u16 Bs[3][BN * BK];

  const int lane = tid & 63;
  const int wm = (tid >> 6) >> 1;
  const int wn = (tid >> 6) & 1;

#pragma unroll
  for (int i = 0; i < FM; ++i)
#pragma unroll
    for (int j = 0; j < FN; ++j)
      acc[i][j] = (f32x4){0.f, 0.f, 0.f, 0.f};

  auto stage = [&](int buf, int k0) {
#pragma unroll
    for (int c = tid; c < BM * BK / 8; c += 256) {
      const int r  = c >> 2;
      const int kk = (c & 3) << 3;
      __builtin_amdgcn_global_load_lds(
          (const __attribute__((address_space(1))) uint32_t*)(Ab + (long)r * K + k0 + kk),
          (__attribute__((address_space(3))) uint32_t*)(&As[buf][c * 8]), 16, 0, 0);
    }
#pragma unroll
    for (int c = tid; c < BN * BK / 8; c += 256) {
      const int r  = c >> 2;
      const int kk = (c & 3) << 3;
      __builtin_amdgcn_global_load_lds(
          (const __attribute__((address_space(1))) uint32_t*)(Bb + (long)r * K + k0 + kk),
          (__attribute__((address_space(3))) uint32_t*)(&Bs[buf][c * 8]), 16, 0, 0);
    }
  };

  const int nt = K / BK;
  stage(0, 0);
  if (nt > 1) stage(1, BK);
  if (nt > 2) stage(2, 2 * BK);

  for (int t = 0; t < nt; ++t) {
    if (t + 2 < nt)      asm volatile("s_waitcnt vmcnt(8)" ::: "memory");
    else if (t + 1 < nt) asm volatile("s_waitcnt vmcnt(4)" ::: "memory");
    else                 asm volatile("s_waitcnt vmcnt(0)" ::: "memory");
    asm volatile("s_barrier" ::: "memory");
    __builtin_amdgcn_sched_barrier(0);

    const int cur = t % 3;
    bf16x8 af[FM], bfv[FN];
#pragma unroll
    for (int i = 0; i < FM; ++i)
      af[i] = *(const bf16x8*)&As[cur][(wm * (BM/2) + i*16 + (lane & 15)) * BK + ((lane >> 4) << 3)];
#pragma unroll
    for (int j = 0; j < FN; ++j)
      bfv[j] = *(const bf16x8*)&Bs[cur][(wn * (BN/2) + j*16 + (lane & 15)) * BK + ((lane >> 4) << 3)];
#pragma unroll
    for (int i = 0; i < FM; ++i)
#pragma unroll
      for (int j = 0; j < FN; ++j)
        acc[i][j] = __builtin_amdgcn_mfma_f32_16x16x32_bf16(af[i], bfv[j], acc[i][j], 0, 0, 0);

    __builtin_amdgcn_sched_barrier(0);
    asm volatile("s_barrier" ::: "memory");
    __builtin_amdgcn_sched_barrier(0);
    if (t + 3 < nt) stage(cur, (t + 3) * BK);
  }
}

// ---------------------------------------------------------------------------
// Fused projection pair (epilogue routes 512-col ranges; V head-transposed)
// ---------------------------------------------------------------------------
struct ProjSet {
  const u16 *A, *W, *bE, *bQ, *bK, *bV;
  u16 *H, *Q, *Kc, *VT;
  int ntokLog, mtiles;
};

__global__ __launch_bounds__(256, 3) void proj_pair(ProjSet s0, ProjSet s1)
{
  const ProjSet S = blockIdx.z ? s1 : s0;
  if ((int)blockIdx.x >= S.mtiles) return;
  const int tid = threadIdx.x;
  const int lane = tid & 63;
  const int wm = (tid >> 6) >> 1, wn = (tid >> 6) & 1;
  const int r16 = lane & 15, rr4 = (lane >> 4) << 2;
  const long row0 = (long)blockIdx.x * 128;
  const long col0 = (long)blockIdx.y * 128;

  f32x4 acc[4][4];
  gemm_core<128,128>(S.A + row0 * 512, S.W + col0 * 512, 512, tid, acc);

  const int range = (int)(col0 >> 9);
  const u16* bp = range == 0 ? S.bE : range == 1 ? S.bQ : range == 2 ? S.bK : S.bV;
  u16* dst = range == 0 ? S.H : range == 1 ? S.Q : S.Kc;
  const int ntok = 1 << S.ntokLog;

#pragma unroll
  for (int i = 0; i < 4; ++i) {
    const long gr0 = row0 + wm*64 + i*16 + rr4;
#pragma unroll
    for (int j = 0; j < 4; ++j) {
      const int cr = (int)(col0 & 511) + wn*64 + j*16 + r16;
      const float badd = us2f(bp[cr]);
      if (range == 3) {
        const long b = gr0 >> S.ntokLog;
        const long t0 = gr0 & (ntok - 1);
        u16x4 pk;
#pragma unroll
        for (int r = 0; r < 4; ++r) pk[r] = f2us(acc[i][j][r] + badd);
        *(u16x4*)&S.VT[((long)b * 512 + cr) * ntok + t0] = pk;
      } else if (range == 0) {
#pragma unroll
        for (int r = 0; r < 4; ++r) {
          float v = acc[i][j][r] + badd;
          v = v / (1.f + __expf(-v));
          dst[(gr0 + r) * 512 + cr] = f2us(v);
        }
      } else {
#pragma unroll
        for (int r = 0; r < 4; ++r)
          dst[(gr0 + r) * 512 + cr] = f2us(acc[i][j][r] + badd);
      }
    }
  }
}

// ---------------------------------------------------------------------------
struct Gm { const u16* A; const u16* Bt; const u16* bias; u16* C; int mtiles; };

template<int SILU>
__global__ __launch_bounds__(256, 3) void gemm_pair(Gm g0, Gm g1, int ldc, int K)
{
  const Gm G = blockIdx.z ? g1 : g0;
  if ((int)blockIdx.x >= G.mtiles) return;
  const int tid = threadIdx.x;
  const int lane = tid & 63;
  const int wm = (tid >> 6) >> 1, wn = (tid >> 6) & 1;
  const int r16 = lane & 15, rr4 = (lane >> 4) << 2;
  const long row0 = (long)blockIdx.x * 128;
  const long col0 = (long)blockIdx.y * 128;

  f32x4 acc[4][4];
  gemm_core<128,128>(G.A + row0 * (long)K, G.Bt + col0 * (long)K, K, tid, acc);

#pragma unroll
  for (int i = 0; i < 4; ++i) {
    const long gr0 = row0 + wm*64 + i*16 + rr4;
#pragma unroll
    for (int j = 0; j < 4; ++j) {
      const long gc = col0 + wn*64 + j*16 + r16;
      const float badd = us2f(G.bias[gc]);
#pragma unroll
      for (int r = 0; r < 4; ++r) {
        float v = acc[i][j][r] + badd;
        if (SILU) v = v / (1.f + __expf(-v));
        G.C[(gr0 + r) * (long)ldc + gc] = f2us(v);
      }
    }
  }
}

// ---------------------------------------------------------------------------
// Fused attention (round-8/11 proven version: separate template kernels)
// ---------------------------------------------------------------------------
template<int NKV, int RPW>
__global__ __launch_bounds__(256) void attn_fused(
    const u16* __restrict__ Qp, const u16* __restrict__ Kp,
    const u16* __restrict__ Vt, const float* __restrict__ lb,
    u16* __restrict__ Aout, int M)
{
  constexpr int NC = NKV >> 7;
  constexpr int FI = RPW / 16;
  constexpr int NS = 4 * FI;
  constexpr int QT = 4 * RPW;
  constexpr int PLD = 136;
  __shared__ __align__(16) u16 Ps[4][RPW][PLD];

  const int tid  = threadIdx.x;
  const int lane = tid & 63;
  const int w    = tid >> 6;
  const int bh = blockIdx.y;
  const int b = bh >> 3, h = bh & 7;
  const long q0 = (long)blockIdx.x * QT;

  const u16* Qb = Qp + ((long)b * M + q0) * DM + h * DHEAD;
  const u16* Kb = Kp + (long)b * NKV * DM + h * DHEAD;
  const u16* Vb = Vt + ((long)b * DM + h * DHEAD) * NKV;
  const float* lbb = lb + (long)b * NKV;

  const int r16 = lane & 15;
  const int k8  = (lane >> 4) << 3;
  const int rr4 = (lane >> 4) << 2;
  const float SCALE = 0.125f;

  bf16x8 qa[FI][2];
#pragma unroll
  for (int i = 0; i < FI; ++i)
#pragma unroll
    for (int kc = 0; kc < 2; ++kc)
      qa[i][kc] = *(const bf16x8*)&Qb[(long)(w*RPW + i*16 + r16) * DM + kc*32 + k8];

  f32x4 acc_o[FI][4];
#pragma unroll
  for (int i = 0; i < FI; ++i)
#pragma unroll
    for (int jo = 0; jo < 4; ++jo)
      acc_o[i][jo] = (f32x4){0.f, 0.f, 0.f, 0.f};
  float mrow[NS], lrow[NS];
#pragma unroll
  for (int s = 0; s < NS; ++s) { mrow[s] = -1e30f; lrow[s] = 0.f; }

#pragma unroll
  for (int c = 0; c < NC; ++c) {
    const int t0 = c * 128;
    f32x4 acc_s[FI][8];
#pragma unroll
    for (int i = 0; i < FI; ++i)
#pragma unroll
      for (int j = 0; j < 8; ++j)
        acc_s[i][j] = (f32x4){0.f, 0.f, 0.f, 0.f};
#pragma unroll
    for (int j = 0; j < 8; ++j) {
      const long trow = t0 + j*16 + r16;
      bf16x8 kb0 = *(const bf16x8*)&Kb[trow * DM + k8];
      bf16x8 kb1 = *(const bf16x8*)&Kb[trow * DM + 32 + k8];
#pragma unroll
      for (int i = 0; i < FI; ++i) {
        acc_s[i][j] = __builtin_amdgcn_mfma_f32_16x16x32_bf16(qa[i][0], kb0, acc_s[i][j], 0, 0, 0);
        acc_s[i][j] = __builtin_amdgcn_mfma_f32_16x16x32_bf16(qa[i][1], kb1, acc_s[i][j], 0, 0, 0);
      }
    }

    float lbv[8];
#pragma unroll
    for (int j = 0; j < 8; ++j) lbv[j] = lbb[t0 + j*16 + r16];
    float pm[NS];
#pragma unroll
    for (int s = 0; s < NS; ++s) pm[s] = -1e30f;
#pragma unroll
    for (int i = 0; i < FI; ++i)
#pragma unroll
      for (int j = 0; j < 8; ++j)
#pragma unroll
        for (int r = 0; r < 4; ++r) {
          float v = acc_s[i][j][r] * SCALE + lbv[j];
          acc_s[i][j][r] = v;
          pm[i*4 + r] = fmaxf(pm[i*4 + r], v);
        }
#pragma unroll
    for (int s = 0; s < NS; ++s) {
#pragma unroll
      for (int o = 1; o < 16; o <<= 1) pm[s] = fmaxf(pm[s], __shfl_xor(pm[s], o));
    }
    float sc[NS];
#pragma unroll
    for (int s = 0; s < NS; ++s) {
      const float mn = fmaxf(mrow[s], pm[s]);
      sc[s] = __expf(mrow[s] - mn);
      mrow[s] = mn;
      lrow[s] *= sc[s];
    }
#pragma unroll
    for (int i = 0; i < FI; ++i)
#pragma unroll
      for (int jo = 0; jo < 4; ++jo)
#pragma unroll
        for (int r = 0; r < 4; ++r)
          acc_o[i][jo][r] *= sc[i*4 + r];

    float ls[NS];
#pragma unroll
    for (int s = 0; s < NS; ++s) ls[s] = 0.f;
#pragma unroll
    for (int i = 0; i < FI; ++i)
#pragma unroll
      for (int j = 0; j < 8; ++j)
#pragma unroll
        for (int r = 0; r < 4; ++r) {
          const float p = __expf(acc_s[i][j][r] - mrow[i*4 + r]);
          ls[i*4 + r] += p;
          Ps[w][i*16 + rr4 + r][j*16 + r16] = f2us(p);
        }
#pragma unroll
    for (int s = 0; s < NS; ++s) {
#pragma unroll
      for (int o = 1; o < 16; o <<= 1) ls[s] += __shfl_xor(ls[s], o);
      lrow[s] += ls[s];
    }

    asm volatile("s_waitcnt lgkmcnt(0)" ::: "memory");
    __builtin_amdgcn_sched_barrier(0);

#pragma unroll
    for (int kc = 0; kc < 4; ++kc) {
      bf16x8 pa[FI];
#pragma unroll
      for (int i = 0; i < FI; ++i)
        pa[i] = *(const bf16x8*)&Ps[w][i*16 + r16][kc*32 + k8];
#pragma unroll
      for (int jo = 0; jo < 4; ++jo) {
        bf16x8 vb = *(const bf16x8*)&Vb[(long)(jo*16 + r16) * NKV + t0 + kc*32 + k8];
#pragma unroll
        for (int i = 0; i < FI; ++i)
          acc_o[i][jo] = __builtin_amdgcn_mfma_f32_16x16x32_bf16(pa[i], vb, acc_o[i][jo], 0, 0, 0);
      }
    }
    __builtin_amdgcn_sched_barrier(0);
  }

  float linv[NS];
#pragma unroll
  for (int s = 0; s < NS; ++s) linv[s] = 1.f / lrow[s];
  u16* Ob = Aout + ((long)b * M + q0) * DM + h * DHEAD;
#pragma unroll
  for (int i = 0; i < FI; ++i)
#pragma unroll
    for (int jo = 0; jo < 4; ++jo)
#pragma unroll
      for (int r = 0; r < 4; ++r) {
        const long row = w*RPW + i*16 + rr4 + r;
        Ob[row * DM + jo*16 + r16] = f2us(acc_o[i][jo][r] * linv[i*4 + r]);
      }
}

// ---------------------------------------------------------------------------
struct LnR { const u16* X; const u16* P; const u16* g; const u16* b; u16* out; int rows; };

__global__ __launch_bounds__(256) void ln_res_pair(LnR a0, LnR a1)
{
  const LnR A = blockIdx.z ? a1 : a0;
  const int row = blockIdx.x * 4 + (threadIdx.x >> 6);
  if (row >= A.rows) return;
  const int lane = threadIdx.x & 63;
  const u16* pr = A.P + (long)row * DM;
  const u16* xr = A.X + (long)row * DM;
  float v[8], s = 0.f, s2 = 0.f;
#pragma unroll
  for (int i = 0; i < 8; ++i) {
    const int jx = i * 64 + lane;
    float t = us2f(pr[jx]) + us2f(xr[jx]);
    v[i] = t; s += t; s2 += t * t;
  }
#pragma unroll
  for (int o = 32; o; o >>= 1) { s += __shfl_xor(s, o); s2 += __shfl_xor(s2, o); }
  const float mean = s * (1.f / DM);
  const float var  = s2 * (1.f / DM) - mean * mean;
  const float rstd = rsqrtf(fmaxf(var, 0.f) + 1e-5f);
#pragma unroll
  for (int i = 0; i < 8; ++i) {
    const int jx = i * 64 + lane;
    A.out[(long)row * DM + jx] = f2us((v[i] - mean) * rstd * us2f(A.g[jx]) + us2f(A.b[jx]));
  }
}

// ---------------------------------------------------------------------------
struct LnF { const u16* P; const u16* g; const u16* b; long oofs; int rows; };

__global__ __launch_bounds__(256) void ln_final_pair(LnF a0, LnF a1,
                                                     void* __restrict__ outb,
                                                     const int* __restrict__ flag)
{
  const LnF A = blockIdx.z ? a1 : a0;
  const int row = blockIdx.x * 4 + (threadIdx.x >> 6);
  if (row >= A.rows) return;
  const int lane = threadIdx.x & 63;
  const u16* pr = A.P + (long)row * DM;
  float v[8], s = 0.f, s2 = 0.f;
#pragma unroll
  for (int i = 0; i < 8; ++i) {
    const int jx = i * 64 + lane;
    float t = us2f(pr[jx]);
    v[i] = t; s += t; s2 += t * t;
  }
#pragma unroll
  for (int o = 32; o; o >>= 1) { s += __shfl_xor(s, o); s2 += __shfl_xor(s2, o); }
  const float mean = s * (1.f / DM);
  const float var  = s2 * (1.f / DM) - mean * mean;
  const float rstd = rsqrtf(fmaxf(var, 0.f) + 1e-5f);
  const int isf32 = flag[0];
#pragma unroll
  for (int i = 0; i < 8; ++i) {
    const int jx = i * 64 + lane;
    const float ov = (v[i] - mean) * rstd * us2f(A.g[jx]) + us2f(A.b[jx]);
    if (isf32) ((float*)outb)[A.oofs + (long)row * DM + jx] = ov;
    else       ((u16*)outb)[A.oofs + (long)row * DM + jx] = f2us(ov);
  }
}

// ---------------------------------------------------------------------------
struct Gt { const u16* H; const u16* W2; const u16* b2; long oofs; float* lb; int rows; };

__global__ __launch_bounds__(256) void gate_pair(Gt a0, Gt a1,
                                                 const int* __restrict__ kptr,
                                                 void* __restrict__ outb,
                                                 const int* __restrict__ flag)
{
  const Gt A = blockIdx.z ? a1 : a0;
  const int row = blockIdx.x * 4 + (threadIdx.x >> 6);
  if (row >= A.rows) return;
  const int lane = threadIdx.x & 63;
  const u16* hr = A.H + (long)row * DM;
  float p1 = 0.f, p2 = 0.f, p3 = 0.f;
#pragma unroll
  for (int i = 0; i < 8; ++i) {
    const int idx = i * 64 + lane;
    const float hv = us2f(hr[idx]);
    const u16x4 w = *(const u16x4*)&A.W2[idx * 4];
    p1 += hv * us2f(w[1]);
    p2 += hv * us2f(w[2]); p3 += hv * us2f(w[3]);
  }
#pragma unroll
  for (int o = 32; o; o >>= 1) {
    p1 += __shfl_xor(p1, o);
    p2 += __shfl_xor(p2, o); p3 += __shfl_xor(p3, o);
  }
  if (lane == 0) {
    const float nu = p1 + us2f(A.b2[1]);
    const float al = p2 + us2f(A.b2[2]);
    const float be = p3 + us2f(A.b2[3]);
    auto sp = [](float x) { return x > 20.f ? x : log1pf(expf(x)); };
    const float spn = sp(nu) + 1e-6f;
    const float spa = sp(al);
    const float spb = sp(be) + 1e-6f;
    const float sig = spb / (spn * spa);
    const float kk = (float)kptr[0];
    float gg = expf(-kk * sig);
    gg = fminf(fmaxf(gg, 0.05f), 1.f);
    if (flag[0]) ((float*)outb)[A.oofs + row] = gg;
    else         ((u16*)outb)[A.oofs + row] = f2us(gg);
    A.lb[row] = logf(gg + 1e-12f);
  }
}

// ---------------------------------------------------------------------------
extern "C" void kernel_launch(void* const* d_in, const int* in_sizes, int n_in,
                              void* d_out, int out_size, void* d_ws, size_t ws_size,
                              hipStream_t stream)
{
  const int* kptr = (const int*)d_in[2];

  uint8_t* base = (uint8_t*)d_ws;
  size_t off = 0;
  auto take = [&](size_t bytes) -> void* {
    void* p = base + off;
    off += (bytes + 255) & ~(size_t)255;
    return p;
  };
  int* FLAG = (int*)take(256);

  const int sizes[42] = {
    2097152, 8388608,
    262144, 512, 2048, 4,
    262144, 512, 2048, 4,
    262144,262144,262144,262144, 512,512,512,512, 512,512,
    262144,262144,262144,262144, 512,512,512,512, 512,512,
    1048576, 2048, 1048576, 512, 512, 512,
    1048576, 2048, 1048576, 512, 512, 512
  };
  u16* canon[42];
  u16* cbase = (u16*)take(17319944ul * 2 + 256);
  {
    unsigned long coff = 0;
    for (int i = 0; i < 42; ++i) {
      canon[i] = cbase + coff;
      coff += (unsigned long)((sizes[i] + 7) & ~7);
    }
  }
  const u16 *HdC = canon[0], *HpC = canon[1];
  const u16 *evid_b1 = canon[3], *evid_w2 = canon[4], *evid_b2 = canon[5];
  const u16 *evip_b1 = canon[7], *evip_w2 = canon[8], *evip_b2 = canon[9];
  const u16 *p2d_bq = canon[14], *p2d_bk = canon[15], *p2d_bv = canon[16], *p2d_bo = canon[17];
  const u16 *p2d_lng = canon[18], *p2d_lnb = canon[19];
  const u16 *d2p_bq = canon[24], *d2p_bk = canon[25], *d2p_bv = canon[26], *d2p_bo = canon[27];
  const u16 *d2p_lng = canon[28], *d2p_lnb = canon[29];
  const u16 *ffnd_b1 = canon[31], *ffnd_b2 = canon[33];
  const u16 *ffnd_lng = canon[34], *ffnd_lnb = canon[35];
  const u16 *ffnp_b1 = canon[37], *ffnp_b2 = canon[39];
  const u16 *ffnp_lng = canon[40], *ffnp_lnb = canon[41];

  u16* HpW = (u16*)take((size_t)2048*512*2);
  u16* HdW = (u16*)take((size_t)2048*512*2);
  u16* woT_p = (u16*)take((size_t)512*512*2);
  u16* woT_d = (u16*)take((size_t)512*512*2);
  u16* ffnp_w1T = (u16*)take((size_t)2048*512*2);
  u16* ffnp_w2T = (u16*)take((size_t)512*2048*2);
  u16* ffnd_w1T = (u16*)take((size_t)2048*512*2);
  u16* ffnd_w2T = (u16*)take((size_t)512*2048*2);

  u16* HBUF_p = (u16*)take((size_t)16384*512*2);
  u16* HBUF_d = (u16*)take((size_t)4096*512*2);
  u16* QBUF_p = (u16*)take((size_t)16384*512*2);
  u16* QBUF_d = (u16*)take((size_t)4096*512*2);
  u16* KBUF_p = (u16*)take((size_t)16384*512*2);
  u16* KBUF_d = (u16*)take((size_t)4096*512*2);
  u16* VT_p   = (u16*)take((size_t)16384*512*2);
  u16* VT_d   = (u16*)take((size_t)4096*512*2);
  u16* ABUF_p = (u16*)take((size_t)16384*512*2);
  u16* ABUF_d = (u16*)take((size_t)4096*512*2);
  u16* HP2  = (u16*)take((size_t)16384*512*2);
  u16* HD2  = (u16*)take((size_t)4096*512*2);
  float* LBD  = (float*)take((size_t)NB*TDr*4);
  float* LBP  = (float*)take((size_t)NB*TPr*4);
  if (off > ws_size) return;

  u16* PBUF_p = HBUF_p;
  u16* PBUF_d = HBUF_d;
  u16* SBUF_p = QBUF_p;
  u16* SBUF_d = SBUF_p + (size_t)16384*2048;

  const long O_HD = 0;
  const long O_HP = 2097152;
  const long O_GD = 10485760;
  const long O_GP = 10489856;

  detect_kernel<<<dim3(1), 64, 0, stream>>>((const u16*)d_in[0], FLAG);

  // canonicalize the 28 tensors read directly (the 14 weights go via transpose)
  CvtTable tbl;
  {
    const int skip[14] = {2,6,10,11,12,13,20,21,22,23,30,32,36,38};
    int ii = 0;
    for (int ci = 0; ci < 42; ++ci) {
      bool sk = false;
      for (int s = 0; s < 14; ++s) if (skip[s] == ci) { sk = true; break; }
      if (sk) continue;
      tbl.d[ii].src = d_in[ci < 2 ? ci : ci + 1];
      tbl.d[ii].dst_off = (unsigned long)(canon[ci] - cbase);
      tbl.d[ii].n = sizes[ci];
      ++ii;
    }
  }
  cvt_kernel<<<dim3(64, 28), 256, 0, stream>>>(tbl, cbase, FLAG);

  // transpose the 14 weights straight from raw input (dtype via flag)
  TTable tt;
  {
    const TTab tts[14] = {
      {d_in[7],  HpW + 0*512*512, 512, 512},   // evip_w1
      {d_in[11], HpW + 1*512*512, 512, 512},   // p2d_wq
      {d_in[22], HpW + 2*512*512, 512, 512},   // d2p_wk
      {d_in[23], HpW + 3*512*512, 512, 512},   // d2p_wv
      {d_in[3],  HdW + 0*512*512, 512, 512},   // evid_w1
      {d_in[21], HdW + 1*512*512, 512, 512},   // d2p_wq
      {d_in[12], HdW + 2*512*512, 512, 512},   // p2d_wk
      {d_in[13], HdW + 3*512*512, 512, 512},   // p2d_wv
      {d_in[14], woT_p, 512, 512},             // p2d_wo
      {d_in[24], woT_d, 512, 512},             // d2p_wo
      {d_in[37], ffnp_w1T, 512, 2048},         // ffnp_w1
      {d_in[39], ffnp_w2T, 2048, 512},         // ffnp_w2
      {d_in[31], ffnd_w1T, 512, 2048},         // ffnd_w1
      {d_in[33], ffnd_w2T, 2048, 512},         // ffnd_w2
    };
    for (int i = 0; i < 14; ++i) tt.d[i] = tts[i];
  }
  transpose_all<<<dim3(16, 16, 14), 256, 0, stream>>>(tt, FLAG);

  // ---- fused projections ----
  ProjSet sp{HpC, HpW, evip_b1, p2d_bq, d2p_bk, d2p_bv,
             HBUF_p, QBUF_p, KBUF_p, VT_p, 10, 128};
  ProjSet sd{HdC, HdW, evid_b1, d2p_bq, p2d_bk, p2d_bv,
             HBUF_d, QBUF_d, KBUF_d, VT_d, 8, 32};
  proj_pair<<<dim3(128, 16, 2), 256, 0, stream>>>(sp, sd);

  // ---- gates ----
  Gt gp{HBUF_p, evip_w2, evip_b2, O_GP, LBP, 16384};
  Gt gd{HBUF_d, evid_w2, evid_b2, O_GD, LBD, 4096};
  gate_pair<<<dim3(4096, 1, 2), 256, 0, stream>>>(gp, gd, kptr, d_out, FLAG);

  // ---- attention (two separate template launches; round-11 proven) ----
  attn_fused<TDr,32><<<dim3(TPr/128, NB*NH), 256, 0, stream>>>(
      QBUF_p, KBUF_d, VT_d, LBD, ABUF_p, TPr);
  attn_fused<TPr,16><<<dim3(TDr/64, NB*NH), 256, 0, stream>>>(
      QBUF_d, KBUF_p, VT_p, LBP, ABUF_d, TDr);

  // ---- output projections ----
  Gm wp{ABUF_p, woT_p, p2d_bo, PBUF_p, 128};
  Gm wd{ABUF_d, woT_d, d2p_bo, PBUF_d, 32};
  gemm_pair<0><<<dim3(128, 4, 2), 256, 0, stream>>>(wp, wd, 512, 512);

  // ---- residual LN ----
  LnR lp{HpC, PBUF_p, p2d_lng, p2d_lnb, HP2, 16384};
  LnR ld{HdC, PBUF_d, d2p_lng, d2p_lnb, HD2, 4096};
  ln_res_pair<<<dim3(4096, 1, 2), 256, 0, stream>>>(lp, ld);

  // ---- FFN1 (SiLU) ----
  Gm f1p{HP2, ffnp_w1T, ffnp_b1, SBUF_p, 128};
  Gm f1d{HD2, ffnd_w1T, ffnd_b1, SBUF_d, 32};
  gemm_pair<1><<<dim3(128, 16, 2), 256, 0, stream>>>(f1p, f1d, 2048, 512);

  // ---- FFN2 ----
  Gm f2p{SBUF_p, ffnp_w2T, ffnp_b2, PBUF_p, 128};
  Gm f2d{SBUF_d, ffnd_w2T, ffnd_b2, PBUF_d, 32};
  gemm_pair<0><<<dim3(128, 4, 2), 256, 0, stream>>>(f2p, f2d, 512, 2048);

  // ---- final LN -> d_out ----
  LnF fp{PBUF_p, ffnp_lng, ffnp_lnb, O_HP, 16384};
  LnF fd{PBUF_d, ffnd_lng, ffnd_lnb, O_HD, 4096};
  ln_final_pair<<<dim3(4096, 1, 2), 256, 0, stream>>>(fp, fd, d_out, FLAG);
}